// Round 12
// baseline (45.587 us; speedup 1.0000x reference)
//
#include <hip/hip_runtime.h>
#include <hip/hip_bf16.h>
#include <math.h>

#define NC 195              // number of countries
#define WCHUNKS 4           // chunks per wave; 4 rows per chunk
#define WAVE_ROWS 16        // rows per wave
#define BLOCK_ROWS 64       // 4 waves * 16 rows
#define F4_PER_WCHUNK 195   // 4 rows * 195 floats / 4 = 195 float4 (3120 B)

// ---- DPP 16-lane butterfly (VALU pipe; r10-proven) ----
template<int CTRL>
__device__ __forceinline__ float dpp_f(float v) {
    int i = __float_as_int(v);
    return __int_as_float(__builtin_amdgcn_update_dpp(i, i, CTRL, 0xF, 0xF, false));
}
template<int CTRL>
__device__ __forceinline__ int dpp_i(int v) {
    return __builtin_amdgcn_update_dpp(v, v, CTRL, 0xF, 0xF, false);
}

__device__ __forceinline__ float hav_scaled(float lat1, float lon1, float lat2, float lon2) {
    const float d2r = 0.017453292519943295f;
    lat1 *= d2r; lon1 *= d2r; lat2 *= d2r; lon2 *= d2r;
    float sdlat = sinf(0.5f * (lat2 - lat1));
    float sdlon = sinf(0.5f * (lon2 - lon1));
    float a = sdlat * sdlat + cosf(lat1) * cosf(lat2) * sdlon * sdlon;
    a = fminf(fmaxf(a, 0.0f), 1.0f);
    return (2.0f * 6371.0f / 500.0f) * asinf(sqrtf(a));  // 2*R*asin(sqrt(a))/500
}

// Kernel B: wave-private LDS strips — ZERO barriers in the hot loop.
// Each wave stages its own 4-row chunk (195 float4) into its private 3120B
// strip, prefetches the next chunk in registers, computes via 16-lane groups
// + DPP butterflies. In-wave LDS ordering (lgkmcnt) replaces __syncthreads;
// waves free-run and stalls decorrelate across 32 waves/CU.
__global__ __launch_bounds__(256) void main_kernel(const float4* __restrict__ logits4,
                                                   const int* __restrict__ target,
                                                   const float* __restrict__ coords,
                                                   float* __restrict__ partials) {
    __shared__ float lds[4 * 780];   // 4 waves x 780 floats = 12480 B
    __shared__ float wpart[16];
    const int t = threadIdx.x;
    const int wave = t >> 6;
    const int lane = t & 63;
    const int u = lane & 15;         // lane within 16-lane row group
    const int g = lane >> 4;         // row group within wave (0..3)
    float* __restrict__ wlds = lds + wave * 780;
    float4* wlds4 = (float4*)wlds;

    const long long rows0 = (long long)blockIdx.x * BLOCK_ROWS + wave * WAVE_ROWS;
    const long long gq = (rows0 >> 2) * NC;   // float4 index of this wave's chunk 0

    // prologue: stage chunk 0 into the wave-private strip (no barrier needed)
    float4 n0 = logits4[gq + lane];
    float4 n1 = logits4[gq + lane + 64];
    float4 n2 = logits4[gq + lane + 128];
    float4 n3;
    if (lane < 3) n3 = logits4[gq + lane + 192];
    wlds4[lane] = n0; wlds4[lane + 64] = n1; wlds4[lane + 128] = n2;
    if (lane < 3) wlds4[lane + 192] = n3;

    const float* __restrict__ rowp = wlds + g * NC;
    float acc = 0.0f;

    for (int c = 0; c < WCHUNKS; ++c) {
        const bool has_next = (c + 1 < WCHUNKS);
        if (has_next) {              // issue next chunk's loads under compute
            const long long nb = gq + (long long)(c + 1) * F4_PER_WCHUNK;
            n0 = logits4[nb + lane];
            n1 = logits4[nb + lane + 64];
            n2 = logits4[nb + lane + 128];
            if (lane < 3) n3 = logits4[nb + lane + 192];
        }

        // in-wave LDS reads of chunk c (precede the chunk c+1 writes in program order)
        float x[13];
        #pragma unroll
        for (int k = 0; k < 12; ++k) x[k] = rowp[u + 16 * k];
        x[12] = (u < 3) ? rowp[192 + u] : -INFINITY;

        // lane-local max + argmax (first occurrence)
        float m = x[0]; int mi = u;
        #pragma unroll
        for (int k = 1; k < 13; ++k) {
            if (x[k] > m) { m = x[k]; mi = u + 16 * k; }
        }
        // DPP butterfly: (max, min-index) over the 16-lane group
        {
            float om; int oi;
            om = dpp_f<0xB1>(m);  oi = dpp_i<0xB1>(mi);
            if (om > m || (om == m && oi < mi)) { m = om; mi = oi; }
            om = dpp_f<0x4E>(m);  oi = dpp_i<0x4E>(mi);
            if (om > m || (om == m && oi < mi)) { m = om; mi = oi; }
            om = dpp_f<0x141>(m); oi = dpp_i<0x141>(mi);
            if (om > m || (om == m && oi < mi)) { m = om; mi = oi; }
            om = dpp_f<0x140>(m); oi = dpp_i<0x140>(mi);
            if (om > m || (om == m && oi < mi)) { m = om; mi = oi; }
        }
        float s = 0.0f;
        #pragma unroll
        for (int k = 0; k < 13; ++k) s += __expf(x[k] - m);
        s += dpp_f<0xB1>(s);
        s += dpp_f<0x4E>(s);
        s += dpp_f<0x141>(s);
        s += dpp_f<0x140>(s);

        if (u == 0) {
            const long long row = rows0 + c * 4 + g;
            int tg = target[row];                    // 256B/block region, L1-resident
            float ce = (m + __logf(s)) - rowp[tg];   // lse - x_target (LDS read, pre-write)
            acc += ce + hav_scaled(coords[2 * mi], coords[2 * mi + 1],
                                   coords[2 * tg], coords[2 * tg + 1]);
        }

        if (has_next) {              // overwrite own strip; in-wave lgkmcnt ordering suffices
            wlds4[lane] = n0; wlds4[lane + 64] = n1; wlds4[lane + 128] = n2;
            if (lane < 3) wlds4[lane + 192] = n3;
        }
    }

    if (u == 0) wpart[wave * 4 + g] = acc;
    __syncthreads();                 // single barrier per block (epilogue)
    if (t == 0) {
        float v = 0.0f;
        #pragma unroll
        for (int j = 0; j < 16; ++j) v += wpart[j];
        partials[blockIdx.x] = v;
    }
}

// Kernel C: single block reduces 4096 partials, writes mean
__global__ __launch_bounds__(1024) void reduce_kernel(const float* __restrict__ partials,
                                                      float inv_b, float* __restrict__ out) {
    float s = partials[threadIdx.x] + partials[threadIdx.x + 1024]
            + partials[threadIdx.x + 2048] + partials[threadIdx.x + 3072];
    #pragma unroll
    for (int off = 32; off > 0; off >>= 1) s += __shfl_xor(s, off);
    __shared__ float ws[16];
    if ((threadIdx.x & 63) == 0) ws[threadIdx.x >> 6] = s;
    __syncthreads();
    if (threadIdx.x == 0) {
        float tot = 0.0f;
        #pragma unroll
        for (int w = 0; w < 16; ++w) tot += ws[w];
        out[0] = tot * inv_b;
    }
}

extern "C" void kernel_launch(void* const* d_in, const int* in_sizes, int n_in,
                              void* d_out, int out_size, void* d_ws, size_t ws_size,
                              hipStream_t stream) {
    const float* logits = (const float*)d_in[0];
    const int*   target = (const int*)d_in[1];
    const float* coords = (const float*)d_in[2];
    float* out = (float*)d_out;

    const int B = in_sizes[1];               // 262144
    const int n_blocks = B / BLOCK_ROWS;     // 4096

    float* partials = (float*)d_ws;          // ws layout: partials[4096]

    main_kernel<<<n_blocks, 256, 0, stream>>>((const float4*)logits, target, coords, partials);
    reduce_kernel<<<1, 1024, 0, stream>>>(partials, 1.0f / (float)B, out);
}